// Round 18
// baseline (87.087 us; speedup 1.0000x reference)
//
#include <hip/hip_runtime.h>
#include <hip/hip_bf16.h>

#define N 8192
#define D 128
#define NSPLIT 16
#define KVSPLIT (N / NSPLIT)   // 512 keys per block
#define KVBLK 64
#define NT (KVSPLIT / KVBLK)   // 8 tiles
#define L2E 1.442695041f

typedef __attribute__((ext_vector_type(8))) _Float16 half8;
typedef __attribute__((ext_vector_type(2))) __fp16 fp16x2;
typedef __attribute__((ext_vector_type(16))) float f32x16;

union H8 { fp16x2 h2[4]; half8 h8; };

__device__ __forceinline__ float fexp2(float x) {
    float r; asm("v_exp_f32 %0, %1" : "=v"(r) : "v"(x)); return r;
}

// ---- fused preprocessing: Q cvt (blocks 0-511), K cvt (512-1023), V transpose (1024-1279)
__global__ void prep_kernel(const float* __restrict__ Q, const float* __restrict__ K,
                            const float* __restrict__ V, _Float16* __restrict__ Qh,
                            _Float16* __restrict__ Kh, _Float16* __restrict__ Vtp) {
    __shared__ _Float16 tile[64][65];
    const int bid = blockIdx.x;
    const int tid = threadIdx.x;
    if (bid < 1024) {
        const float4* src = (const float4*)(bid < 512 ? Q : K);
        _Float16* dst = (bid < 512) ? Qh : Kh;
        const int b = bid & 511;
#pragma unroll
        for (int p = 0; p < 2; ++p) {
            int i = b * 512 + p * 256 + tid;
            float4 v = src[i];
            ushort4 o;
            o.x = __builtin_bit_cast(ushort, (_Float16)v.x);
            o.y = __builtin_bit_cast(ushort, (_Float16)v.y);
            o.z = __builtin_bit_cast(ushort, (_Float16)v.z);
            o.w = __builtin_bit_cast(ushort, (_Float16)v.w);
            *reinterpret_cast<ushort4*>(dst + (size_t)i * 4) = o;
        }
    } else {
        const int vbid = bid - 1024;
        const int k0 = (vbid & 127) * 64;
        const int d0 = (vbid >> 7) * 64;
#pragma unroll
        for (int p = 0; p < 16; ++p) {
            int flat = p * 256 + tid;
            int r = flat >> 6, cc = flat & 63;
            tile[r][cc] = (_Float16)(V[(size_t)(k0 + r) * D + d0 + cc]);
        }
        __syncthreads();
#pragma unroll
        for (int p = 0; p < 16; ++p) {
            int flat = p * 256 + tid;
            int dd = flat >> 6, kl = flat & 63;
            int kk = kl & 31;
            int s32 = 16 * (kk >> 4) + 8 * ((kk >> 2) & 1) + 4 * ((kk >> 3) & 1) + (kk & 3);
            Vtp[(size_t)(d0 + dd) * N + k0 + (kl & 32) + s32] = tile[kl][dd];
        }
    }
}

// ---- stage one 64-key K/V tile into LDS (256 threads; linear dest, inv-swizzled src)
#define STAGE(kdst_, vdst_, kbase_)                                                   \
    {                                                                                 \
        _Pragma("unroll")                                                             \
        for (int p = 0; p < 4; ++p) {                                                 \
            int c4 = p * 256 + tid;                                                   \
            int row = c4 >> 4, chs = c4 & 15;                                         \
            int cc = (chs & 8) | ((chs & 7) ^ (row & 7));                             \
            __builtin_amdgcn_global_load_lds(                                         \
                (const __attribute__((address_space(1))) void*)(Kh + (size_t)((kbase_) + row) * D + cc * 8), \
                (__attribute__((address_space(3))) void*)((kdst_) + c4 * 8), 16, 0, 0);              \
        }                                                                             \
        _Pragma("unroll")                                                             \
        for (int p = 0; p < 4; ++p) {                                                 \
            int c4 = p * 256 + tid;                                                   \
            int dd = c4 >> 3, chs = c4 & 7;                                           \
            int cc = chs ^ (dd & 7);                                                  \
            __builtin_amdgcn_global_load_lds(                                         \
                (const __attribute__((address_space(1))) void*)(Vtp + (size_t)dd * N + (kbase_) + cc * 8),   \
                (__attribute__((address_space(3))) void*)((vdst_) + c4 * 8), 16, 0, 0);              \
        }                                                                             \
    }

// per-qset online softmax + pack; OB_ = compile-time oacc base (0 or 4)
#define SOFTMAX_PACK(S_, MR_, LR_, OB_, PK_)                                          \
    {                                                                                 \
        float mx[8];                                                                  \
        _Pragma("unroll")                                                             \
        for (int r = 0; r < 8; ++r) mx[r] = fmaxf(S_[r], S_[r + 8]);                  \
        _Pragma("unroll")                                                             \
        for (int sd = 4; sd > 0; sd >>= 1)                                            \
            _Pragma("unroll")                                                         \
            for (int r = 0; r < sd; ++r) mx[r] = fmaxf(mx[r], mx[r + sd]);            \
        float pmax = fmaxf(mx[0], __shfl_xor(mx[0], 32));                             \
        if (!__all(pmax <= MR_ + 8.0f)) {                                             \
            float nm = fmaxf(MR_, pmax);                                              \
            float scl = fexp2((MR_ - nm) * L2E);                                      \
            LR_ *= scl;                                                               \
            _Pragma("unroll")                                                         \
            for (int dt = 0; dt < 4; ++dt)                                            \
                _Pragma("unroll")                                                     \
                for (int r = 0; r < 16; ++r) oacc[(OB_) + dt][r] *= scl;              \
            MR_ = nm;                                                                 \
        }                                                                             \
        const float nml = -MR_ * L2E;                                                 \
        _Pragma("unroll")                                                             \
        for (int r = 0; r < 16; ++r) S_[r] = fexp2(__builtin_fmaf(S_[r], L2E, nml));  \
        float tsum[8];                                                                \
        _Pragma("unroll")                                                             \
        for (int r = 0; r < 8; ++r) tsum[r] = S_[r] + S_[r + 8];                      \
        _Pragma("unroll")                                                             \
        for (int sd = 4; sd > 0; sd >>= 1)                                            \
            _Pragma("unroll")                                                         \
            for (int r = 0; r < sd; ++r) tsum[r] += tsum[r + sd];                     \
        LR_ += tsum[0] + __shfl_xor(tsum[0], 32);                                     \
        _Pragma("unroll")                                                             \
        for (int i = 0; i < 4; ++i) {                                                 \
            PK_[0].h2[i] = __builtin_amdgcn_cvt_pkrtz(S_[2 * i], S_[2 * i + 1]);      \
            PK_[1].h2[i] = __builtin_amdgcn_cvt_pkrtz(S_[8 + 2 * i], S_[8 + 2 * i + 1]); \
        }                                                                             \
    }

// ---- main kernel: 4 waves x 64 q-rows (256 q/block), KVBLK=64, 2 blocks/CU ----
// Each kf/vf LDS read feeds TWO MFMAs (qset A and B): LDS reads per unit work halved.
__launch_bounds__(256, 2)
__global__ void fa_kernel(const _Float16* __restrict__ Qh, const _Float16* __restrict__ Kh,
                          const _Float16* __restrict__ Vtp, _Float16* __restrict__ Oph,
                          float* __restrict__ Mpart, float* __restrict__ Lpart) {
    __shared__ __align__(16) _Float16 smem[32768];  // K dbuf 2x16KB + V dbuf 2x16KB = 64 KB

    const int tid  = threadIdx.x;
    const int w    = tid >> 6;
    const int lane = tid & 63;
    const int h    = lane >> 5;
    const int c    = lane & 31;
    const int bid  = blockIdx.x;
    const int split = bid & (NSPLIT - 1);   // XCD = bid%8 -> splits pinned to XCDs
    const int bx   = bid >> 4;
    const int q0w  = bx * 256 + w * 64;     // wave owns 64 q-rows
    const int kv0  = split * KVSPLIT;

    // Q fragments for both qsets: qaA = Q[q0w+c], qaB = Q[q0w+32+c]
    half8 qaA[8], qaB[8];
    {
        const _Float16* qrA = Qh + (size_t)(q0w + c) * D + h * 8;
        const _Float16* qrB = Qh + (size_t)(q0w + 32 + c) * D + h * 8;
#pragma unroll
        for (int st = 0; st < 8; ++st) {
            qaA[st] = *reinterpret_cast<const half8*>(qrA + st * 16);
            qaB[st] = *reinterpret_cast<const half8*>(qrB + st * 16);
        }
    }

    f32x16 oacc[8];   // [0..3] qset A, [4..7] qset B
#pragma unroll
    for (int i = 0; i < 8; ++i)
#pragma unroll
        for (int r = 0; r < 16; ++r) oacc[i][r] = 0.f;
    float mrunA = -1e30f, lrunA = 0.f, mrunB = -1e30f, lrunB = 0.f;

    STAGE(smem, smem + 16384, kv0);
    __syncthreads();

    for (int t = 0; t < NT; ++t) {
        const int cur = t & 1;
        if (t + 1 < NT)
            STAGE(smem + (cur ^ 1) * 8192, smem + 16384 + (cur ^ 1) * 8192,
                  kv0 + (t + 1) * KVBLK);

        const _Float16* kb = smem + cur * 8192;
        const _Float16* vb = smem + 16384 + cur * 8192;

#pragma unroll
        for (int s = 0; s < 2; ++s) {   // two 32-key subtiles
            // ---- QK: one kf read feeds both qsets ----
            f32x16 sA, sB;
#pragma unroll
            for (int r = 0; r < 16; ++r) { sA[r] = 0.f; sB[r] = 0.f; }
            __builtin_amdgcn_s_setprio(1);
#pragma unroll
            for (int st = 0; st < 8; ++st) {
                int ch = st * 2 + h;
                int pos = (ch & 8) | ((ch & 7) ^ (c & 7));
                half8 kf = *reinterpret_cast<const half8*>(kb + (s * 32 + c) * 128 + pos * 8);
                sA = __builtin_amdgcn_mfma_f32_32x32x16_f16(kf, qaA[st], sA, 0, 0, 0);
                sB = __builtin_amdgcn_mfma_f32_32x32x16_f16(kf, qaB[st], sB, 0, 0, 0);
            }
            __builtin_amdgcn_s_setprio(0);

            // ---- per-qset online softmax + pack ----
            H8 pkA[2], pkB[2];
            SOFTMAX_PACK(sA, mrunA, lrunA, 0, pkA)
            SOFTMAX_PACK(sB, mrunB, lrunB, 4, pkB)

            // ---- PV: one vf read feeds both qsets ----
            __builtin_amdgcn_s_setprio(1);
#pragma unroll
            for (int j = 0; j < 2; ++j) {
                int ch = s * 4 + j * 2 + h;
#pragma unroll
                for (int dt = 0; dt < 4; ++dt) {
                    int dd = dt * 32 + c;
                    int pos = ch ^ (dd & 7);
                    half8 vf = *reinterpret_cast<const half8*>(vb + dd * 64 + pos * 8);
                    oacc[dt]     = __builtin_amdgcn_mfma_f32_32x32x16_f16(vf, pkA[j].h8, oacc[dt], 0, 0, 0);
                    oacc[4 + dt] = __builtin_amdgcn_mfma_f32_32x32x16_f16(vf, pkB[j].h8, oacc[4 + dt], 0, 0, 0);
                }
            }
            __builtin_amdgcn_s_setprio(0);
        }

        __syncthreads();   // drains prefetch; protects buffer reuse
    }

    // ---- epilogue: per qset, normalize + transpose via LDS + coalesced fp16 store ----
    __syncthreads();
    float* epi = reinterpret_cast<float*>(smem) + w * 1088;   // 32x33 f32 per wave
    const size_t sbase = (size_t)split * N;
    {
        float inv = 1.0f / lrunA;
#pragma unroll
        for (int dt = 0; dt < 4; ++dt) {
#pragma unroll
            for (int r = 0; r < 16; ++r) {
                int dloc = (r & 3) + 8 * (r >> 2) + 4 * h;
                epi[c * 33 + dloc] = oacc[dt][r] * inv;
            }
#pragma unroll
            for (int it = 0; it < 16; ++it) {
                int j = it * 64 + lane;
                int rr = j >> 5, cc2 = j & 31;
                Oph[(sbase + q0w + rr) * D + dt * 32 + cc2] = (_Float16)epi[rr * 33 + cc2];
            }
        }
    }
    {
        float inv = 1.0f / lrunB;
#pragma unroll
        for (int dt = 0; dt < 4; ++dt) {
#pragma unroll
            for (int r = 0; r < 16; ++r) {
                int dloc = (r & 3) + 8 * (r >> 2) + 4 * h;
                epi[c * 33 + dloc] = oacc[4 + dt][r] * inv;
            }
#pragma unroll
            for (int it = 0; it < 16; ++it) {
                int j = it * 64 + lane;
                int rr = j >> 5, cc2 = j & 31;
                Oph[(sbase + q0w + 32 + rr) * D + dt * 32 + cc2] = (_Float16)epi[rr * 33 + cc2];
            }
        }
    }
    if (h == 0) {
        Mpart[sbase + q0w + c] = mrunA;
        Lpart[sbase + q0w + c] = lrunA;
        Mpart[sbase + q0w + 32 + c] = mrunB;
        Lpart[sbase + q0w + 32 + c] = lrunB;
    }
}

// ---- merge the NSPLIT partials ----
__global__ void fa_merge(const _Float16* __restrict__ Oph, const float* __restrict__ Mpart,
                         const float* __restrict__ Lpart, float* __restrict__ O) {
    int idx = blockIdx.x * 256 + threadIdx.x;   // over N*D
    int q = idx >> 7;
    int d = idx & 127;
    float m[NSPLIT];
    float M = -1e30f;
#pragma unroll
    for (int s = 0; s < NSPLIT; ++s) {
        m[s] = Mpart[s * N + q];
        M = fmaxf(M, m[s]);
    }
    float acc = 0.f, wsum = 0.f;
#pragma unroll
    for (int s = 0; s < NSPLIT; ++s) {
        float wgt = fexp2((m[s] - M) * L2E) * Lpart[s * N + q];
        acc += wgt * (float)Oph[((size_t)s * N + q) * D + d];
        wsum += wgt;
    }
    O[idx] = acc / wsum;
}

extern "C" void kernel_launch(void* const* d_in, const int* in_sizes, int n_in,
                              void* d_out, int out_size, void* d_ws, size_t ws_size,
                              hipStream_t stream) {
    const float* Q = (const float*)d_in[0];
    const float* K = (const float*)d_in[1];
    const float* V = (const float*)d_in[2];
    float* O = (float*)d_out;

    _Float16* Qh = (_Float16*)d_ws;                         // 2 MB
    _Float16* Kh = Qh + (size_t)N * D;                      // 2 MB
    _Float16* Vtp = Kh + (size_t)N * D;                     // 2 MB
    _Float16* Oph = Vtp + (size_t)N * D;                    // 32 MB (fp16 partials x16)
    float* Mpart = (float*)(Oph + (size_t)NSPLIT * N * D);  // 512 KB
    float* Lpart = Mpart + (size_t)NSPLIT * N;              // 512 KB

    hipLaunchKernelGGL(prep_kernel, dim3(1280), dim3(256), 0, stream,
                       Q, K, V, Qh, Kh, Vtp);
    hipLaunchKernelGGL(fa_kernel, dim3((N / 256) * NSPLIT), dim3(256), 0, stream,
                       Qh, Kh, Vtp, Oph, Mpart, Lpart);
    hipLaunchKernelGGL(fa_merge, dim3(N * D / 256), dim3(256), 0, stream,
                       Oph, Mpart, Lpart, O);
}